// Round 7
// baseline (222.527 us; speedup 1.0000x reference)
//
#include <hip/hip_runtime.h>
#include <hip/hip_bf16.h>
#include <stdint.h>

typedef unsigned short u16;
typedef __bf16 v8bf __attribute__((ext_vector_type(8)));
typedef float  v4f  __attribute__((ext_vector_type(4)));

#define N_ROWS 8192
#define C_REAL 10000
#define C_PAD  10240   /* 80 * 128 */
#define D_DIM  512
#define BM 128
#define BN 128
#define BK 64
#define KTILES (D_DIM / BK)   /* 8 */

/* LDS map (bytes): 2 slots of 32KB (A 16KB @0 = 128 rows x 128B swizzled,
   B 16KB @16384), then f2s @65536, c2s @66048, labs @66560. Total 67072
   => 2 blocks/CU (135KB < 160KB), VGPR ~190/wave => 8 waves/CU fit. */
#define SM_SLOT  32768
#define SM_BOFF  16384
#define SM_F2    65536
#define SM_C2    66048
#define SM_LAB   66560
#define SM_TOTAL 67072
static_assert(2 * SM_TOTAL <= 160 * 1024, "want 2 blocks/CU");

#define BARRIER() do { asm volatile("" ::: "memory"); \
                       __builtin_amdgcn_s_barrier();  \
                       asm volatile("" ::: "memory"); } while (0)
#define MFMA(d, a, b) d = __builtin_amdgcn_mfma_f32_16x16x32_bf16(a, b, d, 0, 0, 0)
#define GLL(gp, lp) __builtin_amdgcn_global_load_lds( \
    (const __attribute__((address_space(1))) void*)(gp), \
    (__attribute__((address_space(3))) void*)(lp), 16, 0, 0)

__device__ __forceinline__ unsigned pack2bf(float a, float b) {
    unsigned short ua = __builtin_bit_cast(unsigned short, (__bf16)a);
    unsigned short ub = __builtin_bit_cast(unsigned short, (__bf16)b);
    return (unsigned)ua | ((unsigned)ub << 16);
}

// One wave per row: L2-normalize, write bf16 row + f32 sum-of-squares-of-normalized.
// Rows >= nreal are padding: bf16 zeros, o2 = 1e30 (=> dis = -5e30 => exp = 0).
__global__ __launch_bounds__(256) void norm_rows_kernel(
    const float* __restrict__ x, u16* __restrict__ ob, float* __restrict__ o2,
    int nreal, int ntotal)
{
    int row  = blockIdx.x * 4 + (threadIdx.x >> 6);
    int lane = threadIdx.x & 63;
    if (row >= ntotal) return;
    uint2* orow = (uint2*)(ob + (size_t)row * D_DIM);
    if (row >= nreal) {
        uint2 z; z.x = 0u; z.y = 0u;
        orow[lane] = z; orow[64 + lane] = z;
        if (lane == 0) o2[row] = 1e30f;
        return;
    }
    const float4* xr = (const float4*)(x + (size_t)row * D_DIM);
    float4 v0 = xr[lane];
    float4 v1 = xr[64 + lane];
    float s = v0.x*v0.x + v0.y*v0.y + v0.z*v0.z + v0.w*v0.w
            + v1.x*v1.x + v1.y*v1.y + v1.z*v1.z + v1.w*v1.w;
    #pragma unroll
    for (int m = 1; m < 64; m <<= 1) s += __shfl_xor(s, m, 64);
    float nrm = sqrtf(s);
    float inv = 1.0f / fmaxf(nrm, 1e-12f);
    if (lane == 0) o2[row] = s * inv * inv;
    uint2 p0, p1;
    p0.x = pack2bf(v0.x * inv, v0.y * inv);
    p0.y = pack2bf(v0.z * inv, v0.w * inv);
    p1.x = pack2bf(v1.x * inv, v1.y * inv);
    p1.y = pack2bf(v1.z * inv, v1.w * inv);
    orow[lane]      = p0;
    orow[64 + lane] = p1;
}

// Exact (f32) positive-class distance: one wave per row, gathered center row.
__global__ __launch_bounds__(256) void pos_exact_kernel(
    const float* __restrict__ feat, const float* __restrict__ cent,
    const int* __restrict__ labels, float* __restrict__ pose)
{
    int row  = blockIdx.x * 4 + (threadIdx.x >> 6);
    int lane = threadIdx.x & 63;
    int lab  = labels[row];
    const float4* fr = (const float4*)(feat + (size_t)row * D_DIM);
    const float4* cr = (const float4*)(cent + (size_t)lab * D_DIM);
    float sf = 0.f, sc = 0.f, sd = 0.f;
    #pragma unroll
    for (int i = 0; i < 2; ++i) {
        float4 a = fr[i * 64 + lane];
        float4 b = cr[i * 64 + lane];
        sf += a.x*a.x + a.y*a.y + a.z*a.z + a.w*a.w;
        sc += b.x*b.x + b.y*b.y + b.z*b.z + b.w*b.w;
        sd += a.x*b.x + a.y*b.y + a.z*b.z + a.w*b.w;
    }
    #pragma unroll
    for (int m = 1; m < 64; m <<= 1) {
        sf += __shfl_xor(sf, m, 64);
        sc += __shfl_xor(sc, m, 64);
        sd += __shfl_xor(sd, m, 64);
    }
    if (lane == 0) {
        float nf = fmaxf(sqrtf(sf), 1e-12f);
        float nc = fmaxf(sqrtf(sc), 1e-12f);
        float invf = 1.f / nf, invc = 1.f / nc;
        float f2n = sf * invf * invf;
        float c2n = sc * invc * invc;
        float dtn = sd * invf * invc;
        pose[row] = -5.0f * (f2n + c2n - 2.0f * dtn);
    }
}

// 128x128x(BK=64) 4-wave MFMA GEMM, double-buffered, 2 blocks/CU:
// cross-block overlap (m114) hides per-tile drains and per-block
// prologue/epilogue that a 1-block/CU shape exposes (rounds 2-6 all
// plateaued ~12.4K cyc/K-tile at 1 block/CU regardless of schedule).
// Same XOR-8 swizzle (0 conflicts, rounds 2/6). Grid (80,64): 80%8==0
// => XCD = x%8 => per-XCD B-slice 1.3MB + window A ~1MB < 4MB L2.
// rowsum split into 8 column-residue slices to kill cross-XCD atomic
// line bouncing. Fused exp epilogue.
__global__ __launch_bounds__(256, 2) void gemm_kernel(
    const u16* __restrict__ A, const u16* __restrict__ B,
    const float* __restrict__ f2, const float* __restrict__ c2,
    const int* __restrict__ labels,
    float* __restrict__ rowsum, float* __restrict__ posdis)
{
    extern __shared__ char sm[];
    const int rowBase = blockIdx.y * BM;
    const int colBase = blockIdx.x * BN;
    const int tid  = threadIdx.x;
    const int lane = tid & 63;
    const int w    = tid >> 6;      // 0..3
    const int wr   = w >> 1;        // 0..1 : 64-row group
    const int wc   = w & 1;         // 0..1 : 64-col group
    const int l15  = lane & 15;
    const int h4   = lane >> 4;

    // ---- staging offsets: per matrix-tile 1024 x 16B chunks; thread covers
    // c = tid + i*256 (i=0..3): r = c>>3 = (tid>>3)+i*32, pc = c&7 = tid&7,
    // lc = pc ^ (r&7) with (r&7) invariant under +i*32.
    const int r0  = tid >> 3;                       // 0..31
    const int lc0 = (tid & 7) ^ (r0 & 7);
    const size_t gOff = (size_t)r0 * D_DIM + lc0 * 8;   // elements; +16384/i
    const int d0 = tid * 16;                            // LDS bytes; +4096/i
    const u16* Abase = A + (size_t)rowBase * D_DIM;
    const u16* Bbase = B + (size_t)colBase * D_DIM;

    auto stage = [&](int k, char* dst) {
        const u16* Ak = Abase + k * BK + gOff;   // +32 rows = +16384 elems
        const u16* Bk = Bbase + k * BK + gOff;
        GLL(Ak,         dst + d0);
        GLL(Ak + 16384, dst + d0 + 4096);
        GLL(Ak + 32768, dst + d0 + 8192);
        GLL(Ak + 49152, dst + d0 + 12288);
        GLL(Bk,         dst + SM_BOFF + d0);
        GLL(Bk + 16384, dst + SM_BOFF + d0 + 4096);
        GLL(Bk + 32768, dst + SM_BOFF + d0 + 8192);
        GLL(Bk + 49152, dst + SM_BOFF + d0 + 12288);
    };

    // ---- fragment read bases; fragment row = wr*64 + m*16 + l15 has
    // row&7 == l15&7, so swizzled column = ((ks*4+h4) ^ (l15&7)).
    const int s0 = ((h4)     ^ (l15 & 7)) << 4;
    const int s1 = ((4 + h4) ^ (l15 & 7)) << 4;
    const int aB0 = wr * 8192 + l15 * 128 + s0;
    const int aB1 = wr * 8192 + l15 * 128 + s1;
    const int bB0 = SM_BOFF + wc * 8192 + l15 * 128 + s0;
    const int bB1 = SM_BOFF + wc * 8192 + l15 * 128 + s1;

    // ---- prologue: epilogue tables + tile 0; full drain once ----
    if (tid < 128) {
        ((float*)(sm + SM_F2))[tid] = f2[rowBase + tid];
        ((int*)(sm + SM_LAB))[tid]  = labels[rowBase + tid];
    } else {
        ((float*)(sm + SM_C2))[tid - 128] = c2[colBase + (tid - 128)];
    }
    stage(0, sm);
    __syncthreads();

    v4f acc[4][4];
    #pragma unroll
    for (int m = 0; m < 4; ++m)
        #pragma unroll
        for (int n = 0; n < 4; ++n) acc[m][n] = (v4f){0.f, 0.f, 0.f, 0.f};

    #pragma unroll 2
    for (int k = 0; k < KTILES; ++k) {
        const char* smc = sm + (k & 1) * SM_SLOT;
        char*      bufn = sm + ((k + 1) & 1) * SM_SLOT;

        if (k + 1 < KTILES) stage(k + 1, bufn);

        v8bf a[4], b[4];
        // ---- ks = 0 ----
        #pragma unroll
        for (int m = 0; m < 4; ++m) a[m] = *(const v8bf*)(smc + aB0 + m * 2048);
        #pragma unroll
        for (int n = 0; n < 4; ++n) b[n] = *(const v8bf*)(smc + bB0 + n * 2048);
        __builtin_amdgcn_s_setprio(1);
        #pragma unroll
        for (int m = 0; m < 4; ++m)
            #pragma unroll
            for (int n = 0; n < 4; ++n)
                MFMA(acc[m][n], a[m], b[n]);
        __builtin_amdgcn_s_setprio(0);
        // ---- ks = 1 ----
        #pragma unroll
        for (int m = 0; m < 4; ++m) a[m] = *(const v8bf*)(smc + aB1 + m * 2048);
        #pragma unroll
        for (int n = 0; n < 4; ++n) b[n] = *(const v8bf*)(smc + bB1 + n * 2048);
        __builtin_amdgcn_s_setprio(1);
        #pragma unroll
        for (int m = 0; m < 4; ++m)
            #pragma unroll
            for (int n = 0; n < 4; ++n)
                MFMA(acc[m][n], a[m], b[n]);
        __builtin_amdgcn_s_setprio(0);

        if (k + 1 < KTILES) {
            asm volatile("s_waitcnt vmcnt(0)" ::: "memory");
            BARRIER();
        }
    }

    // Epilogue: dis = -5*(f2 + c2 - 2*dot); exp; per-row sums; label capture.
    float* rs = rowsum + (size_t)(blockIdx.x & 7) * N_ROWS;  // per-XCD slice
    const float* f2s  = (const float*)(sm + SM_F2);
    const float* c2s  = (const float*)(sm + SM_C2);
    const int*   labs = (const int*)(sm + SM_LAB);
    #pragma unroll
    for (int m = 0; m < 4; ++m) {
        float s[4] = {0.f, 0.f, 0.f, 0.f};
        const int lr0 = wr * 64 + m * 16 + h4 * 4;
        #pragma unroll
        for (int n = 0; n < 4; ++n) {
            const int lcol = wc * 64 + n * 16 + l15;
            const int gcol = colBase + lcol;
            const float cc = c2s[lcol];
            #pragma unroll
            for (int j = 0; j < 4; ++j) {
                const int lr = lr0 + j;
                float dis = -5.0f * (f2s[lr] + cc - 2.0f * acc[m][n][j]);
                float e = __expf(dis);
                s[j] += e;
                if (labs[lr] == gcol) posdis[rowBase + lr] = dis;
            }
        }
        #pragma unroll
        for (int msk = 1; msk < 16; msk <<= 1) {
            #pragma unroll
            for (int j = 0; j < 4; ++j) s[j] += __shfl_xor(s[j], msk, 64);
        }
        if (l15 == 0) {
            #pragma unroll
            for (int j = 0; j < 4; ++j)
                atomicAdd(&rs[rowBase + lr0 + j], s[j]);
        }
    }
}

// Final scalar reduction: loss and unbiased variance (f64 accumulation).
__global__ __launch_bounds__(256) void finalize_kernel(
    const float* __restrict__ posdis, const float* __restrict__ pose,
    const float* __restrict__ rowsum, const int* __restrict__ labels,
    const float* __restrict__ bias, float* __restrict__ out)
{
    int t = threadIdx.x;
    double sl = 0.0, sp = 0.0, sp2 = 0.0;
    for (int r = t; r < N_ROWS; r += 256) {
        float rsum = 0.f;
        #pragma unroll
        for (int x = 0; x < 8; ++x) rsum += rowsum[x * N_ROWS + r];
        float pd = posdis[r];                 // bf16-path label term (matches rowsum)
        float p  = pose[r] + bias[labels[r]]; // exact-path pos_metric
        float num = __expf(p);
        float den = rsum - __expf(pd) + num;
        sl  += (double)(logf(den) - p);
        sp  += (double)p;
        sp2 += (double)p * (double)p;
    }
    #pragma unroll
    for (int m = 1; m < 64; m <<= 1) {
        sl  += __shfl_xor(sl,  m, 64);
        sp  += __shfl_xor(sp,  m, 64);
        sp2 += __shfl_xor(sp2, m, 64);
    }
    __shared__ double sh[3][4];
    int w = t >> 6, lane = t & 63;
    if (lane == 0) { sh[0][w] = sl; sh[1][w] = sp; sh[2][w] = sp2; }
    __syncthreads();
    if (t == 0) {
        sl  = sh[0][0] + sh[0][1] + sh[0][2] + sh[0][3];
        sp  = sh[1][0] + sh[1][1] + sh[1][2] + sh[1][3];
        sp2 = sh[2][0] + sh[2][1] + sh[2][2] + sh[2][3];
        const double N = (double)N_ROWS;
        double mean = sp / N;
        double var  = (sp2 - N * mean * mean) / (N - 1.0);
        double loss = sl / N + var;
        out[0] = (float)loss;
        out[1] = (float)var;
    }
}

extern "C" void kernel_launch(void* const* d_in, const int* in_sizes, int n_in,
                              void* d_out, int out_size, void* d_ws, size_t ws_size,
                              hipStream_t stream) {
    const float* features = (const float*)d_in[0];
    const int*   labels   = (const int*)d_in[1];
    const float* centers  = (const float*)d_in[2];
    const float* bias     = (const float*)d_in[3];
    float* out = (float*)d_out;
    char* ws = (char*)d_ws;

    // Workspace layout (16B aligned), ~19.3 MB total.
    u16*   fb     = (u16*)(ws);                 // 8192*512*2  = 8388608
    u16*   cb     = (u16*)(ws + 8388608);       // 10240*512*2 = 10485760
    float* f2     = (float*)(ws + 18874368);    // 8192*4
    float* c2     = (float*)(ws + 18907136);    // 10240*4
    float* rowsum = (float*)(ws + 18948096);    // 8*8192*4 = 262144
    float* posdis = (float*)(ws + 19210240);    // 8192*4
    float* pose   = (float*)(ws + 19243008);    // 8192*4

    hipMemsetAsync(rowsum, 0, 8 * N_ROWS * sizeof(float), stream);

    hipLaunchKernelGGL(norm_rows_kernel, dim3(N_ROWS / 4), dim3(256), 0, stream,
                       features, fb, f2, N_ROWS, N_ROWS);
    hipLaunchKernelGGL(norm_rows_kernel, dim3(C_PAD / 4), dim3(256), 0, stream,
                       centers, cb, c2, C_REAL, C_PAD);
    hipLaunchKernelGGL(pos_exact_kernel, dim3(N_ROWS / 4), dim3(256), 0, stream,
                       features, centers, labels, pose);

    hipFuncSetAttribute(reinterpret_cast<const void*>(gemm_kernel),
                        hipFuncAttributeMaxDynamicSharedMemorySize, SM_TOTAL);
    hipLaunchKernelGGL(gemm_kernel, dim3(C_PAD / BN, N_ROWS / BM), dim3(256), SM_TOTAL, stream,
                       fb, cb, f2, c2, labels, rowsum, posdis);

    hipLaunchKernelGGL(finalize_kernel, dim3(1), dim3(256), 0, stream,
                       posdis, pose, rowsum, labels, bias, out);
}

// Round 9
// 183.407 us; speedup vs baseline: 1.2133x; 1.2133x over previous
//
#include <hip/hip_runtime.h>
#include <hip/hip_bf16.h>
#include <stdint.h>

typedef unsigned short u16;
typedef __bf16 v8bf __attribute__((ext_vector_type(8)));
typedef float  v4f  __attribute__((ext_vector_type(4)));

#define N_ROWS 8192
#define C_REAL 10000
#define C_PAD  10240   /* 80 * 128 */
#define D_DIM  512
#define BM 128
#define BN 128
#define BK 64
#define KTILES (D_DIM / BK)   /* 8 */

/* LDS map (bytes): ONE 32KB tile buffer (A 16KB @0 = 128 rows x 128B swizzled,
   B 16KB @16384), then f2s @32768, c2s @33280, labs @33792. Total 34304
   => 4 blocks/CU by LDS; __launch_bounds__(256,4) => 4 waves/SIMD from 4
   independent blocks (cross-block overlap hides stage drains, m114). */
#define SM_BOFF  16384
#define SM_F2    32768
#define SM_C2    33280
#define SM_LAB   33792
#define SM_TOTAL 34304
static_assert(4 * SM_TOTAL <= 160 * 1024, "want 4 blocks/CU");

#define BARRIER() do { asm volatile("" ::: "memory"); \
                       __builtin_amdgcn_s_barrier();  \
                       asm volatile("" ::: "memory"); } while (0)
#define MFMA(d, a, b) d = __builtin_amdgcn_mfma_f32_16x16x32_bf16(a, b, d, 0, 0, 0)
#define GLL(gp, lp) __builtin_amdgcn_global_load_lds( \
    (const __attribute__((address_space(1))) void*)(gp), \
    (__attribute__((address_space(3))) void*)(lp), 16, 0, 0)

__device__ __forceinline__ unsigned pack2bf(float a, float b) {
    unsigned short ua = __builtin_bit_cast(unsigned short, (__bf16)a);
    unsigned short ub = __builtin_bit_cast(unsigned short, (__bf16)b);
    return (unsigned)ua | ((unsigned)ub << 16);
}

// One wave per row: L2-normalize, write bf16 row + f32 sum-of-squares-of-normalized.
// Rows >= nreal are padding: bf16 zeros, o2 = 1e30 (=> dis = -5e30 => exp = 0).
__global__ __launch_bounds__(256) void norm_rows_kernel(
    const float* __restrict__ x, u16* __restrict__ ob, float* __restrict__ o2,
    int nreal, int ntotal)
{
    int row  = blockIdx.x * 4 + (threadIdx.x >> 6);
    int lane = threadIdx.x & 63;
    if (row >= ntotal) return;
    uint2* orow = (uint2*)(ob + (size_t)row * D_DIM);
    if (row >= nreal) {
        uint2 z; z.x = 0u; z.y = 0u;
        orow[lane] = z; orow[64 + lane] = z;
        if (lane == 0) o2[row] = 1e30f;
        return;
    }
    const float4* xr = (const float4*)(x + (size_t)row * D_DIM);
    float4 v0 = xr[lane];
    float4 v1 = xr[64 + lane];
    float s = v0.x*v0.x + v0.y*v0.y + v0.z*v0.z + v0.w*v0.w
            + v1.x*v1.x + v1.y*v1.y + v1.z*v1.z + v1.w*v1.w;
    #pragma unroll
    for (int m = 1; m < 64; m <<= 1) s += __shfl_xor(s, m, 64);
    float nrm = sqrtf(s);
    float inv = 1.0f / fmaxf(nrm, 1e-12f);
    if (lane == 0) o2[row] = s * inv * inv;
    uint2 p0, p1;
    p0.x = pack2bf(v0.x * inv, v0.y * inv);
    p0.y = pack2bf(v0.z * inv, v0.w * inv);
    p1.x = pack2bf(v1.x * inv, v1.y * inv);
    p1.y = pack2bf(v1.z * inv, v1.w * inv);
    orow[lane]      = p0;
    orow[64 + lane] = p1;
}

// Exact (f32) positive-class distance: one wave per row, gathered center row.
__global__ __launch_bounds__(256) void pos_exact_kernel(
    const float* __restrict__ feat, const float* __restrict__ cent,
    const int* __restrict__ labels, float* __restrict__ pose)
{
    int row  = blockIdx.x * 4 + (threadIdx.x >> 6);
    int lane = threadIdx.x & 63;
    int lab  = labels[row];
    const float4* fr = (const float4*)(feat + (size_t)row * D_DIM);
    const float4* cr = (const float4*)(cent + (size_t)lab * D_DIM);
    float sf = 0.f, sc = 0.f, sd = 0.f;
    #pragma unroll
    for (int i = 0; i < 2; ++i) {
        float4 a = fr[i * 64 + lane];
        float4 b = cr[i * 64 + lane];
        sf += a.x*a.x + a.y*a.y + a.z*a.z + a.w*a.w;
        sc += b.x*b.x + b.y*b.y + b.z*b.z + b.w*b.w;
        sd += a.x*b.x + a.y*b.y + a.z*b.z + a.w*b.w;
    }
    #pragma unroll
    for (int m = 1; m < 64; m <<= 1) {
        sf += __shfl_xor(sf, m, 64);
        sc += __shfl_xor(sc, m, 64);
        sd += __shfl_xor(sd, m, 64);
    }
    if (lane == 0) {
        float nf = fmaxf(sqrtf(sf), 1e-12f);
        float nc = fmaxf(sqrtf(sc), 1e-12f);
        float invf = 1.f / nf, invc = 1.f / nc;
        float f2n = sf * invf * invf;
        float c2n = sc * invc * invc;
        float dtn = sd * invf * invc;
        pose[row] = -5.0f * (f2n + c2n - 2.0f * dtn);
    }
}

// 128x128x(BK=64) 4-wave MFMA GEMM, SINGLE 32KB buffer, 4 blocks/CU.
// K-loop fully unrolled; K-advance is a compile-time constant pointer
// offset (aP + k*64) that the compiler folds into the instruction's
// offset: field (m254) => zero address VALU, and the pointer-path GLL
// semantics that rounds 1-7 validated (round 8's builtin-offset arg
// corrupted LDS — reverted). Per tile: {lgkmcnt(0), barrier, 8 GLL,
// vmcnt(0), barrier, 16 ds_read_b128 + 32 MFMA}; the drain of one
// block hides under the other 3 blocks' compute (m114).
// XOR-8 swizzle (0 conflicts, rounds 6/7). Grid (80,64): 80%8==0 =>
// XCD = x%8 => per-XCD B-slice 1.3MB + window A ~1MB < 4MB L2.
__global__ __launch_bounds__(256, 4) void gemm_kernel(
    const u16* __restrict__ A, const u16* __restrict__ B,
    const float* __restrict__ f2, const float* __restrict__ c2,
    const int* __restrict__ labels,
    float* __restrict__ rowsum, float* __restrict__ posdis)
{
    extern __shared__ char sm[];
    const int rowBase = blockIdx.y * BM;
    const int colBase = blockIdx.x * BN;
    const int tid  = threadIdx.x;
    const int lane = tid & 63;
    const int w    = tid >> 6;      // 0..3
    const int wr   = w >> 1;        // 0..1 : 64-row group
    const int wc   = w & 1;         // 0..1 : 64-col group
    const int l15  = lane & 15;
    const int h4   = lane >> 4;

    // ---- staging geometry: per matrix-tile 1024 x 16B chunks; thread covers
    // c = tid + i*256 (i=0..3): r = (tid>>3)+i*32, pc = tid&7,
    // lc = pc ^ (r&7) with (r&7) invariant under +i*32.
    const int r0  = tid >> 3;                       // 0..31
    const int lc0 = (tid & 7) ^ (r0 & 7);
    const size_t gOff = (size_t)r0 * D_DIM + lc0 * 8;   // elements
    const u16* aP = A + (size_t)rowBase * D_DIM + gOff; // +16384 elems per i
    const u16* bP = B + (size_t)colBase * D_DIM + gOff;
    char* lA = sm + tid * 16;                           // +4096 per i
    char* lB = sm + SM_BOFF + tid * 16;

    // K-advance KOFS is in ELEMENTS, a compile-time constant per unroll.
    #define STAGE8(KOFS) do { \
        GLL(aP + (KOFS),         lA);         \
        GLL(aP + (KOFS) + 16384, lA + 4096);  \
        GLL(aP + (KOFS) + 32768, lA + 8192);  \
        GLL(aP + (KOFS) + 49152, lA + 12288); \
        GLL(bP + (KOFS),         lB);         \
        GLL(bP + (KOFS) + 16384, lB + 4096);  \
        GLL(bP + (KOFS) + 32768, lB + 8192);  \
        GLL(bP + (KOFS) + 49152, lB + 12288); \
    } while (0)

    // ---- fragment read bases (loop-invariant, single buffer); fragment
    // row = wr*64 + m*16 + l15 has row&7 == l15&7, so swizzled byte col
    // = ((ks*4+h4) ^ (l15&7)) * 16.
    const int s0 = ((h4)     ^ (l15 & 7)) << 4;
    const int s1 = ((4 + h4) ^ (l15 & 7)) << 4;
    const int aB0 = wr * 8192 + l15 * 128 + s0;
    const int aB1 = wr * 8192 + l15 * 128 + s1;
    const int bB0 = SM_BOFF + wc * 8192 + l15 * 128 + s0;
    const int bB1 = SM_BOFF + wc * 8192 + l15 * 128 + s1;

    // ---- prologue: epilogue tables + tile 0; full drain once ----
    if (tid < 128) {
        ((float*)(sm + SM_F2))[tid] = f2[rowBase + tid];
        ((int*)(sm + SM_LAB))[tid]  = labels[rowBase + tid];
    } else {
        ((float*)(sm + SM_C2))[tid - 128] = c2[colBase + (tid - 128)];
    }
    STAGE8(0);
    __syncthreads();

    v4f acc[4][4];
    #pragma unroll
    for (int m = 0; m < 4; ++m)
        #pragma unroll
        for (int n = 0; n < 4; ++n) acc[m][n] = (v4f){0.f, 0.f, 0.f, 0.f};

    auto compute = [&]() {
        v8bf a[4], b[4];
        #pragma unroll
        for (int m = 0; m < 4; ++m) a[m] = *(const v8bf*)(sm + aB0 + m * 2048);
        #pragma unroll
        for (int n = 0; n < 4; ++n) b[n] = *(const v8bf*)(sm + bB0 + n * 2048);
        __builtin_amdgcn_s_setprio(1);
        #pragma unroll
        for (int m = 0; m < 4; ++m)
            #pragma unroll
            for (int n = 0; n < 4; ++n)
                MFMA(acc[m][n], a[m], b[n]);
        __builtin_amdgcn_s_setprio(0);
        #pragma unroll
        for (int m = 0; m < 4; ++m) a[m] = *(const v8bf*)(sm + aB1 + m * 2048);
        #pragma unroll
        for (int n = 0; n < 4; ++n) b[n] = *(const v8bf*)(sm + bB1 + n * 2048);
        __builtin_amdgcn_s_setprio(1);
        #pragma unroll
        for (int m = 0; m < 4; ++m)
            #pragma unroll
            for (int n = 0; n < 4; ++n)
                MFMA(acc[m][n], a[m], b[n]);
        __builtin_amdgcn_s_setprio(0);
    };

    // 8 K-tiles; single buffer reused — all tile-k LDS reads are complete
    // before any wave passes the pre-stage barrier (MFMAs consumed them;
    // explicit lgkmcnt(0) makes it airtight).
    #define NEXT_TILE(KOFS) do { \
        asm volatile("s_waitcnt lgkmcnt(0)" ::: "memory"); \
        BARRIER(); \
        STAGE8(KOFS); \
        asm volatile("s_waitcnt vmcnt(0)" ::: "memory"); \
        BARRIER(); \
        compute(); \
    } while (0)

    compute();
    NEXT_TILE(64);
    NEXT_TILE(128);
    NEXT_TILE(192);
    NEXT_TILE(256);
    NEXT_TILE(320);
    NEXT_TILE(384);
    NEXT_TILE(448);
    #undef NEXT_TILE
    #undef STAGE8

    // Epilogue: dis = -5*(f2 + c2 - 2*dot); exp; per-row sums; label capture.
    float* rs = rowsum + (size_t)(blockIdx.x & 7) * N_ROWS;  // per-XCD slice
    const float* f2s  = (const float*)(sm + SM_F2);
    const float* c2s  = (const float*)(sm + SM_C2);
    const int*   labs = (const int*)(sm + SM_LAB);
    #pragma unroll
    for (int m = 0; m < 4; ++m) {
        float s[4] = {0.f, 0.f, 0.f, 0.f};
        const int lr0 = wr * 64 + m * 16 + h4 * 4;
        #pragma unroll
        for (int n = 0; n < 4; ++n) {
            const int lcol = wc * 64 + n * 16 + l15;
            const int gcol = colBase + lcol;
            const float cc = c2s[lcol];
            #pragma unroll
            for (int j = 0; j < 4; ++j) {
                const int lr = lr0 + j;
                float dis = -5.0f * (f2s[lr] + cc - 2.0f * acc[m][n][j]);
                float e = __expf(dis);
                s[j] += e;
                if (labs[lr] == gcol) posdis[rowBase + lr] = dis;
            }
        }
        #pragma unroll
        for (int msk = 1; msk < 16; msk <<= 1) {
            #pragma unroll
            for (int j = 0; j < 4; ++j) s[j] += __shfl_xor(s[j], msk, 64);
        }
        if (l15 == 0) {
            #pragma unroll
            for (int j = 0; j < 4; ++j)
                atomicAdd(&rs[rowBase + lr0 + j], s[j]);
        }
    }
}

// Final scalar reduction: loss and unbiased variance (f64 accumulation).
__global__ __launch_bounds__(256) void finalize_kernel(
    const float* __restrict__ posdis, const float* __restrict__ pose,
    const float* __restrict__ rowsum, const int* __restrict__ labels,
    const float* __restrict__ bias, float* __restrict__ out)
{
    int t = threadIdx.x;
    double sl = 0.0, sp = 0.0, sp2 = 0.0;
    for (int r = t; r < N_ROWS; r += 256) {
        float rsum = 0.f;
        #pragma unroll
        for (int x = 0; x < 8; ++x) rsum += rowsum[x * N_ROWS + r];
        float pd = posdis[r];                 // bf16-path label term (matches rowsum)
        float p  = pose[r] + bias[labels[r]]; // exact-path pos_metric
        float num = __expf(p);
        float den = rsum - __expf(pd) + num;
        sl  += (double)(logf(den) - p);
        sp  += (double)p;
        sp2 += (double)p * (double)p;
    }
    #pragma unroll
    for (int m = 1; m < 64; m <<= 1) {
        sl  += __shfl_xor(sl,  m, 64);
        sp  += __shfl_xor(sp,  m, 64);
        sp2 += __shfl_xor(sp2, m, 64);
    }
    __shared__ double sh[3][4];
    int w = t >> 6, lane = t & 63;
    if (lane == 0) { sh[0][w] = sl; sh[1][w] = sp; sh[2][w] = sp2; }
    __syncthreads();
    if (t == 0) {
        sl  = sh[0][0] + sh[0][1] + sh[0][2] + sh[0][3];
        sp  = sh[1][0] + sh[1][1] + sh[1][2] + sh[1][3];
        sp2 = sh[2][0] + sh[2][1] + sh[2][2] + sh[2][3];
        const double N = (double)N_ROWS;
        double mean = sp / N;
        double var  = (sp2 - N * mean * mean) / (N - 1.0);
        double loss = sl / N + var;
        out[0] = (float)loss;
        out[1] = (float)var;
    }
}

extern "C" void kernel_launch(void* const* d_in, const int* in_sizes, int n_in,
                              void* d_out, int out_size, void* d_ws, size_t ws_size,
                              hipStream_t stream) {
    const float* features = (const float*)d_in[0];
    const int*   labels   = (const int*)d_in[1];
    const float* centers  = (const float*)d_in[2];
    const float* bias     = (const float*)d_in[3];
    float* out = (float*)d_out;
    char* ws = (char*)d_ws;

    // Workspace layout (16B aligned), ~19.3 MB total.
    u16*   fb     = (u16*)(ws);                 // 8192*512*2  = 8388608
    u16*   cb     = (u16*)(ws + 8388608);       // 10240*512*2 = 10485760
    float* f2     = (float*)(ws + 18874368);    // 8192*4
    float* c2     = (float*)(ws + 18907136);    // 10240*4
    float* rowsum = (float*)(ws + 18948096);    // 8*8192*4 = 262144
    float* posdis = (float*)(ws + 19210240);    // 8192*4
    float* pose   = (float*)(ws + 19243008);    // 8192*4

    hipMemsetAsync(rowsum, 0, 8 * N_ROWS * sizeof(float), stream);

    hipLaunchKernelGGL(norm_rows_kernel, dim3(N_ROWS / 4), dim3(256), 0, stream,
                       features, fb, f2, N_ROWS, N_ROWS);
    hipLaunchKernelGGL(norm_rows_kernel, dim3(C_PAD / 4), dim3(256), 0, stream,
                       centers, cb, c2, C_REAL, C_PAD);
    hipLaunchKernelGGL(pos_exact_kernel, dim3(N_ROWS / 4), dim3(256), 0, stream,
                       features, centers, labels, pose);

    hipFuncSetAttribute(reinterpret_cast<const void*>(gemm_kernel),
                        hipFuncAttributeMaxDynamicSharedMemorySize, SM_TOTAL);
    hipLaunchKernelGGL(gemm_kernel, dim3(C_PAD / BN, N_ROWS / BM), dim3(256), SM_TOTAL, stream,
                       fb, cb, f2, c2, labels, rowsum, posdis);

    hipLaunchKernelGGL(finalize_kernel, dim3(1), dim3(256), 0, stream,
                       posdis, pose, rowsum, labels, bias, out);
}